// Round 2
// baseline (389.325 us; speedup 1.0000x reference)
//
#include <hip/hip_runtime.h>
#include <math.h>

#define N_NODES 200000
#define NGRAPH  512
#define HID     256
#define NTILES  (N_NODES / 16)   // 12500 exactly (200000 % 16 == 0)
#define PARTS   2

typedef __attribute__((ext_vector_type(8))) short s16x8;
typedef __attribute__((ext_vector_type(4))) float f32x4;

__device__ __forceinline__ unsigned short f2bf_rne(float f) {
  unsigned int u = __float_as_uint(f);
  return (unsigned short)((u + 0x7fffu + ((u >> 16) & 1u)) >> 16);
}
__device__ __forceinline__ unsigned int pack2_bf16_rne(float a, float b) {
  unsigned int ua = __float_as_uint(a), ub = __float_as_uint(b);
  unsigned int ra = (ua + 0x7fffu + ((ua >> 16) & 1u)) >> 16;
  unsigned int rb = (ub + 0x7fffu + ((ub >> 16) & 1u)) & 0xffff0000u;
  return ra | rb;
}
__device__ __forceinline__ int lower_bound_batch(const int* __restrict__ batch, int target) {
  int lo = 0, hi = N_NODES;
  while (lo < hi) { int mid = (lo + hi) >> 1; if (batch[mid] < target) lo = mid + 1; else hi = mid; }
  return lo;
}
__device__ __forceinline__ f32x4 vmax4(f32x4 a, f32x4 b) {
  return (f32x4){fmaxf(a[0], b[0]), fmaxf(a[1], b[1]), fmaxf(a[2], b[2]), fmaxf(a[3], b[3])};
}

// ---------------------------------------------------------------------------
// Kernel 1: gate GEMM -> e[i] = exp(g_i), g = relu(x w1 + b1) w2 + b2.
// Softmax is shift-invariant, so raw exp(g) works as the attention weight
// numerator; den is accumulated downstream. g is O(+-5) for N(0,1) data ->
// no overflow. All tiles full (N % 16 == 0) -> no clamping.
// launch_bounds(256,4): 16 waves/CU, all 1024 blocks co-resident. A-pack in
// four 2-kt quarters keeps <=4 float4 in flight so 128 VGPRs suffice.
// ---------------------------------------------------------------------------
__global__ __launch_bounds__(256, 4) void gate_kernel(
    const float* __restrict__ x, const float* __restrict__ w1,
    const float* __restrict__ b1, const float* __restrict__ w2,
    const float* __restrict__ b2, float* __restrict__ ew)
{
  __shared__ __align__(16) short w1T[64 * 264];  // bf16 w1^T [n][k], pitch 264
  const int tid = threadIdx.x;
  const int w = tid >> 6, lane = tid & 63, q = lane >> 4, c = lane & 15;

  for (int i = tid; i < 256 * 64; i += 256) {  // i = k*64 + n, coalesced
    int k = i >> 6, n = i & 63;
    w1T[n * 264 + k] = (short)f2bf_rne(w1[i]);
  }
  __syncthreads();

  float b1v[4], w2v[4];
#pragma unroll
  for (int nt = 0; nt < 4; ++nt) { b1v[nt] = b1[nt * 16 + c]; w2v[nt] = w2[nt * 16 + c]; }
  const float b2v = b2[0];

  const int tstride = gridDim.x << 2;
  for (int t = (blockIdx.x << 2) + w; t < NTILES; t += tstride) {
    const int r0 = t << 4;
    const float* ap = x + (size_t)(r0 + c) * HID + q * 8;
    union { s16x8 v; unsigned int u[4]; } ah[8];
#pragma unroll
    for (int quar = 0; quar < 4; ++quar) {   // 2 kt per step: <=4 float4 live
      float4 t0[2], t1[2];
#pragma unroll
      for (int kk = 0; kk < 2; ++kk) {
        int kt = quar * 2 + kk;
        t0[kk] = *(const float4*)(ap + kt * 32);
        t1[kk] = *(const float4*)(ap + kt * 32 + 4);
      }
#pragma unroll
      for (int kk = 0; kk < 2; ++kk) {
        int kt = quar * 2 + kk;
        ah[kt].u[0] = pack2_bf16_rne(t0[kk].x, t0[kk].y);
        ah[kt].u[1] = pack2_bf16_rne(t0[kk].z, t0[kk].w);
        ah[kt].u[2] = pack2_bf16_rne(t1[kk].x, t1[kk].y);
        ah[kt].u[3] = pack2_bf16_rne(t1[kk].z, t1[kk].w);
      }
    }

    f32x4 acc[4];
#pragma unroll
    for (int nt = 0; nt < 4; ++nt) acc[nt] = (f32x4){0.f, 0.f, 0.f, 0.f};
#pragma unroll
    for (int kt = 0; kt < 8; ++kt) {
#pragma unroll
      for (int nt = 0; nt < 4; ++nt) {
        s16x8 bh = *(const s16x8*)&w1T[(nt * 16 + c) * 264 + kt * 32 + q * 8];
        acc[nt] = __builtin_amdgcn_mfma_f32_16x16x32_bf16(ah[kt].v, bh, acc[nt], 0, 0, 0);
      }
    }

    // D[row=4q+r][col=nt*16+c]; butterfly over c -> gate(row 4q+r) uniform in quad
    float gr[4];
#pragma unroll
    for (int r = 0; r < 4; ++r) {
      float sv = 0.f;
#pragma unroll
      for (int nt = 0; nt < 4; ++nt) {
        float h = acc[nt][r] + b1v[nt];
        h = h > 0.f ? h : 0.f;
        sv += h * w2v[nt];
      }
      sv += __shfl_xor(sv, 1, 64);
      sv += __shfl_xor(sv, 2, 64);
      sv += __shfl_xor(sv, 4, 64);
      sv += __shfl_xor(sv, 8, 64);
      gr[r] = sv + b2v;
    }
    if (c == 0) {
      float4 o = make_float4(__expf(gr[0]), __expf(gr[1]), __expf(gr[2]), __expf(gr[3]));
      *(float4*)(ew + r0 + q * 4) = o;   // rows r0+4q .. r0+4q+3, 16B aligned
    }
  }
}

// ---------------------------------------------------------------------------
// Kernel 2: streaming pool. Block = (segment, half). Lane owns 4 columns,
// waves stride rows, 8 rows (32 load VGPRs) in flight. Weights are the raw
// exp numerators e[i]; den is accumulated here (e is loaded anyway) and the
// division happens in the merge -> no softmax kernel, no rescale, no shuffles.
// launch_bounds(256,4): 128-VGPR cap (body needs ~70 -> no spill), 16 waves/CU,
// all 1024 blocks co-resident. x is L3-hot from kernel 1.
// ---------------------------------------------------------------------------
__global__ __launch_bounds__(256, 4) void pool_pass(
    const float* __restrict__ x, const int* __restrict__ batch,
    const float* __restrict__ ew, float* __restrict__ pbuf)
{
  __shared__ int sb[2];
  __shared__ float sden[4];
  __shared__ __align__(16) float scr[12 * 256];
  const int tid = threadIdx.x;
  const int w = tid >> 6, lane = tid & 63;
  const int seg = blockIdx.x >> 1, p = blockIdx.x & 1;

  if (tid < 2) sb[tid] = lower_bound_batch(batch, seg + tid);
  __syncthreads();
  const int s0 = sb[0], len = sb[1] - s0;
  const int ps = s0 + ((len * p) >> 1);
  const int pe = s0 + ((len * (p + 1)) >> 1);

  f32x4 sum = (f32x4){0.f, 0.f, 0.f, 0.f};
  f32x4 at  = (f32x4){0.f, 0.f, 0.f, 0.f};
  f32x4 mx  = (f32x4){-INFINITY, -INFINITY, -INFINITY, -INFINITY};
  float den = 0.f;

  const float* xp = x + lane * 4;
  int r = ps + w;
  for (; r + 28 < pe; r += 32) {     // 8 rows (stride 4) per iteration
    float4 v[8]; float wv[8];
#pragma unroll
    for (int j = 0; j < 8; ++j) v[j] = *(const float4*)(xp + (size_t)(r + 4 * j) * HID);
#pragma unroll
    for (int j = 0; j < 8; ++j) wv[j] = ew[r + 4 * j];
#pragma unroll
    for (int j = 0; j < 8; ++j) {
      f32x4 f = (f32x4){v[j].x, v[j].y, v[j].z, v[j].w};
      sum = sum + f;
      mx = vmax4(mx, f);
      den += wv[j];
      at[0] = fmaf(wv[j], f[0], at[0]);
      at[1] = fmaf(wv[j], f[1], at[1]);
      at[2] = fmaf(wv[j], f[2], at[2]);
      at[3] = fmaf(wv[j], f[3], at[3]);
    }
  }
  for (; r < pe; r += 4) {
    float4 v = *(const float4*)(xp + (size_t)r * HID);
    float wr = ew[r];
    f32x4 f = (f32x4){v.x, v.y, v.z, v.w};
    sum = sum + f;
    mx = vmax4(mx, f);
    den += wr;
#pragma unroll
    for (int j = 0; j < 4; ++j) at[j] = fmaf(wr, f[j], at[j]);
  }

  // cross-wave merge (weights are plain numerators: just sum)
  {
    float* p0 = scr + (w * 3 + 0) * 256;
    float* p1 = scr + (w * 3 + 1) * 256;
    float* p2 = scr + (w * 3 + 2) * 256;
    *(f32x4*)&p0[lane * 4] = sum;
    *(f32x4*)&p1[lane * 4] = mx;
    *(f32x4*)&p2[lane * 4] = at;
    if (lane == 0) sden[w] = den;
  }
  __syncthreads();
  {
    const int f = tid;
    float S = 0.f, MX = -INFINITY, A = 0.f;
#pragma unroll
    for (int ww = 0; ww < 4; ++ww) {
      S += scr[(ww * 3 + 0) * 256 + f];
      MX = fmaxf(MX, scr[(ww * 3 + 1) * 256 + f]);
      A += scr[(ww * 3 + 2) * 256 + f];
    }
    float* pr = pbuf + (size_t)blockIdx.x * 772;
    pr[f] = S; pr[256 + f] = MX; pr[512 + f] = A;
    if (tid == 0) { pr[768] = (float)(pe - ps); pr[769] = sden[0] + sden[1] + sden[2] + sden[3]; }
  }
}

// ---------------------------------------------------------------------------
// Kernel 3: merge PARTS partials per segment -> z (512 x 768 fp32).
// z_attn = (sum e x) / max(sum e, 1e-16)  (identical to softmax-weighted sum)
// ---------------------------------------------------------------------------
__global__ __launch_bounds__(256) void pool_merge2(
    const float* __restrict__ pbuf, float* __restrict__ zbuf)
{
  const int seg = blockIdx.x, f = threadIdx.x;
  float S = 0.f, A = 0.f, MX = -INFINITY, cnt = 0.f, den = 0.f;
#pragma unroll
  for (int pp = 0; pp < PARTS; ++pp) {
    const float* pr = pbuf + (size_t)(seg * PARTS + pp) * 772;
    S += pr[f];
    MX = fmaxf(MX, pr[256 + f]);
    A += pr[512 + f];
    cnt += pr[768];
    den += pr[769];
  }
  float* zr = zbuf + (size_t)seg * 768;
  zr[f]       = S / fmaxf(cnt, 1.f);
  zr[256 + f] = (cnt > 0.f) ? MX : 0.f;
  zr[512 + f] = A / fmaxf(den, 1e-16f);
}

// ---------------------------------------------------------------------------
// Kernel 4: y = z @ wp + bp, LayerNorm, fp32 out. (unchanged, validated)
// ---------------------------------------------------------------------------
__global__ __launch_bounds__(256) void head_ln(
    const float* __restrict__ zbuf, const float* __restrict__ wp,
    const float* __restrict__ bp, const float* __restrict__ gam,
    const float* __restrict__ bet, float* __restrict__ out)
{
  const int g = blockIdx.x;
  const int tid = threadIdx.x;
  const int w = tid >> 6, lane = tid & 63;
  __shared__ float z[768];
  __shared__ __align__(16) float part[4][256];
  __shared__ float red[256];

  for (int i = tid; i < 768; i += 256) z[i] = zbuf[(size_t)g * 768 + i];
  __syncthreads();

  f32x4 acc = (f32x4){0.f, 0.f, 0.f, 0.f};
  const float4* wp4 = (const float4*)wp;
  const int k0 = w * 192;
#pragma unroll 8
  for (int k = k0; k < k0 + 192; ++k) {
    float4 wv = wp4[(size_t)k * 64 + lane];
    float zk = z[k];
    acc[0] = fmaf(zk, wv.x, acc[0]);
    acc[1] = fmaf(zk, wv.y, acc[1]);
    acc[2] = fmaf(zk, wv.z, acc[2]);
    acc[3] = fmaf(zk, wv.w, acc[3]);
  }
  *(f32x4*)&part[w][lane * 4] = acc;
  __syncthreads();

  const int t = tid;
  float y = bp[t] + part[0][t] + part[1][t] + part[2][t] + part[3][t];

  red[t] = y;
  __syncthreads();
  for (int wd = 128; wd > 0; wd >>= 1) {
    if (t < wd) red[t] += red[t + wd];
    __syncthreads();
  }
  const float mu = red[0] * (1.f / 256.f);
  __syncthreads();
  float d = y - mu;
  red[t] = d * d;
  __syncthreads();
  for (int wd = 128; wd > 0; wd >>= 1) {
    if (t < wd) red[t] += red[t + wd];
    __syncthreads();
  }
  const float var = red[0] * (1.f / 256.f);
  const float is = rsqrtf(var + 1e-5f);
  out[(size_t)g * 256 + t] = fmaf(d * is, gam[t], bet[t]);
}

// ---------------------------------------------------------------------------
extern "C" void kernel_launch(void* const* d_in, const int* in_sizes, int n_in,
                              void* d_out, int out_size, void* d_ws, size_t ws_size,
                              hipStream_t stream) {
  const float* x   = (const float*)d_in[0];
  const int*   bat = (const int*)d_in[1];
  const float* w1  = (const float*)d_in[2];
  const float* b1  = (const float*)d_in[3];
  const float* w2  = (const float*)d_in[4];
  const float* b2  = (const float*)d_in[5];
  const float* wp  = (const float*)d_in[6];
  const float* bp  = (const float*)d_in[7];
  const float* gam = (const float*)d_in[8];
  const float* bet = (const float*)d_in[9];
  float* out = (float*)d_out;

  // ws layout: e (200000 f32) | pbuf (1024*772 f32) | zbuf (512*768 f32)
  float* ebuf = (float*)d_ws;
  float* pbuf = ebuf + N_NODES;
  float* zbuf = pbuf + (size_t)NGRAPH * PARTS * 772;

  hipLaunchKernelGGL(gate_kernel, dim3(1024), dim3(256), 0, stream,
                     x, w1, b1, w2, b2, ebuf);
  hipLaunchKernelGGL(pool_pass, dim3(NGRAPH * PARTS), dim3(256), 0, stream,
                     x, bat, ebuf, pbuf);
  hipLaunchKernelGGL(pool_merge2, dim3(NGRAPH), dim3(256), 0, stream, pbuf, zbuf);
  hipLaunchKernelGGL(head_ln, dim3(NGRAPH), dim3(256), 0, stream,
                     zbuf, wp, bp, gam, bet, out);
}

// Round 3
// 339.738 us; speedup vs baseline: 1.1460x; 1.1460x over previous
//
#include <hip/hip_runtime.h>
#include <math.h>

#define N_NODES 200000
#define NGRAPH  512
#define HID     256
#define NTILES  (N_NODES / 16)   // 12500 exactly
#define NBLK    256              // 1 block/CU (LDS 130 KB -> max 1 resident)
#define NWAVE   (NBLK * 4)       // 1024 waves
#define TPW     (NTILES / NWAVE) // 12 base tiles/wave
#define TREM    (NTILES - NWAVE * TPW)  // 212 waves get one extra

typedef __attribute__((ext_vector_type(8))) short s16x8;
typedef __attribute__((ext_vector_type(4))) float f32x4;

__device__ __forceinline__ unsigned int pack2_bf16_rne(float a, float b) {
  unsigned int ua = __float_as_uint(a), ub = __float_as_uint(b);
  unsigned int ra = (ua + 0x7fffu + ((ua >> 16) & 1u)) >> 16;
  unsigned int rb = (ub + 0x7fffu + ((ub >> 16) & 1u)) & 0xffff0000u;
  return ra | rb;
}
__device__ __forceinline__ int lower_bound_batch(const int* __restrict__ batch, int target) {
  int lo = 0, hi = N_NODES;
  while (lo < hi) { int mid = (lo + hi) >> 1; if (batch[mid] < target) lo = mid + 1; else hi = mid; }
  return lo;
}
// order-preserving float->uint key for atomicMax (works for all finite floats)
__device__ __forceinline__ unsigned fkey(float f) {
  unsigned u = __float_as_uint(f);
  return (u >> 31) ? ~u : (u | 0x80000000u);
}

// ---------------------------------------------------------------------------
// Fused gate+pool, single HBM pass over x via global_load_lds staging.
//  - grid 256 x 256thr; wave-private 2x(16 rows + batch) LDS double buffer
//  - 17 global_load_lds per tile; counted s_waitcnt vmcnt(17) (never 0 mid-loop)
//  - B-fragments (w1 bf16) in 128 registers; NO barriers in the whole kernel
//  - x rows pre-swizzled on the GLOBAL side (rule 21): LDS dest stays linear,
//    reads XOR byte^((row&7)<<4) -> A-frag reads 2-way bank (free)
//  - pool partials flushed per segment with device-scope atomics
// ---------------------------------------------------------------------------
__global__ __launch_bounds__(256, 1) void fused_gate_pool(
    const float* __restrict__ x, const int* __restrict__ batch,
    const float* __restrict__ w1, const float* __restrict__ b1,
    const float* __restrict__ w2, const float* __restrict__ b2,
    float* __restrict__ gsum, unsigned* __restrict__ gmx,
    float* __restrict__ gat, float* __restrict__ gden)
{
  struct Buf { float xrow[16][256]; int bat[64]; };
  __shared__ __align__(16) Buf stg[4][2];   // [wave][dbuf] = 133,120 B

  const int tid = threadIdx.x;
  const int w = tid >> 6, lane = tid & 63, q = lane >> 4, c = lane & 15;
  const int gw = blockIdx.x * 4 + w;

  const int t0   = gw * TPW + (gw < TREM ? gw : TREM);
  const int tend = t0 + TPW + (gw < TREM ? 1 : 0);

  // B fragments in registers: bh[nt][kt] = bf16 w1[k = kt*32+q*8+j][n = nt*16+c]
  s16x8 bh[4][8];
#pragma unroll
  for (int nt = 0; nt < 4; ++nt) {
#pragma unroll
    for (int kt = 0; kt < 8; ++kt) {
      float f[8];
#pragma unroll
      for (int j = 0; j < 8; ++j)
        f[j] = w1[(size_t)(kt * 32 + q * 8 + j) * 64 + nt * 16 + c];
      union { s16x8 v; unsigned u[4]; } tmp;
      tmp.u[0] = pack2_bf16_rne(f[0], f[1]);
      tmp.u[1] = pack2_bf16_rne(f[2], f[3]);
      tmp.u[2] = pack2_bf16_rne(f[4], f[5]);
      tmp.u[3] = pack2_bf16_rne(f[6], f[7]);
      bh[nt][kt] = tmp.v;
    }
  }
  float b1v[4], w2v[4];
#pragma unroll
  for (int nt = 0; nt < 4; ++nt) { b1v[nt] = b1[nt * 16 + c]; w2v[nt] = w2[nt * 16 + c]; }
  const float b2v = b2[0];

  int soff[8];
#pragma unroll
  for (int s = 0; s < 8; ++s) soff[s] = (lane * 16) ^ (s << 4);
  const int csw = (c & 7) << 4;

  f32x4 sum = (f32x4){0.f, 0.f, 0.f, 0.f};
  f32x4 at  = (f32x4){0.f, 0.f, 0.f, 0.f};
  f32x4 mx  = (f32x4){-INFINITY, -INFINITY, -INFINITY, -INFINITY};
  float den = 0.f;
  int curseg = -1;

  auto STAGE = [&](int t, int b) {
    const char* rowbase = (const char*)x + (size_t)t * 16384;
#pragma unroll
    for (int r = 0; r < 16; ++r) {
      const void* gp = rowbase + r * 1024 + soff[r & 7];
      __builtin_amdgcn_global_load_lds(
          (const __attribute__((address_space(1))) void*)gp,
          (__attribute__((address_space(3))) void*)&stg[w][b].xrow[r][0],
          16, 0, 0);
    }
    const void* bp2 = (const void*)(batch + t * 16 + (lane & 15));
    __builtin_amdgcn_global_load_lds(
        (const __attribute__((address_space(1))) void*)bp2,
        (__attribute__((address_space(3))) void*)&stg[w][b].bat[0],
        4, 0, 0);
  };

  auto FLUSH = [&](int seg) {
    float* sp = gsum + (size_t)seg * 256 + lane * 4;
    float* ap = gat  + (size_t)seg * 256 + lane * 4;
    unsigned* mp = gmx + (size_t)seg * 256 + lane * 4;
#pragma unroll
    for (int j = 0; j < 4; ++j) {
      atomicAdd(&sp[j], sum[j]);
      atomicAdd(&ap[j], at[j]);
      atomicMax(&mp[j], fkey(mx[j]));
    }
    if (lane == 0) atomicAdd(&gden[seg], den);
  };

  STAGE(t0, 0);
  STAGE(t0 + 1, 1);

  for (int t = t0; t < tend; ++t) {
    const int b = (t - t0) & 1;
    if (t + 1 < tend) { asm volatile("s_waitcnt vmcnt(17)" ::: "memory"); }
    else              { asm volatile("s_waitcnt vmcnt(0)"  ::: "memory"); }
    __builtin_amdgcn_sched_barrier(0);

    // ---- A fragments from LDS (fp32 -> bf16 pack), row = c, swizzled ----
    const char* rb = (const char*)&stg[w][b].xrow[c][0];
    union { s16x8 v; unsigned u[4]; } ah[8];
#pragma unroll
    for (int kt = 0; kt < 8; ++kt) {
      const int base = kt * 128 + q * 32;
      float4 t0v = *(const float4*)(rb + ((base)      ^ csw));
      float4 t1v = *(const float4*)(rb + ((base + 16) ^ csw));
      ah[kt].u[0] = pack2_bf16_rne(t0v.x, t0v.y);
      ah[kt].u[1] = pack2_bf16_rne(t0v.z, t0v.w);
      ah[kt].u[2] = pack2_bf16_rne(t1v.x, t1v.y);
      ah[kt].u[3] = pack2_bf16_rne(t1v.z, t1v.w);
    }

    f32x4 acc[4];
#pragma unroll
    for (int nt = 0; nt < 4; ++nt) acc[nt] = (f32x4){0.f, 0.f, 0.f, 0.f};
#pragma unroll
    for (int kt = 0; kt < 8; ++kt) {
#pragma unroll
      for (int nt = 0; nt < 4; ++nt)
        acc[nt] = __builtin_amdgcn_mfma_f32_16x16x32_bf16(ah[kt].v, bh[nt][kt], acc[nt], 0, 0, 0);
    }

    // ---- gate epilogue: D[row=4q+r][col=nt*16+c]; butterfly over c ----
    float er[4];
#pragma unroll
    for (int r = 0; r < 4; ++r) {
      float sv = 0.f;
#pragma unroll
      for (int nt = 0; nt < 4; ++nt) {
        float h = acc[nt][r] + b1v[nt];
        h = h > 0.f ? h : 0.f;
        sv += h * w2v[nt];
      }
      sv += __shfl_xor(sv, 1, 64);
      sv += __shfl_xor(sv, 2, 64);
      sv += __shfl_xor(sv, 4, 64);
      sv += __shfl_xor(sv, 8, 64);
      er[r] = __expf(sv + b2v);   // shift-free softmax numerator (|g|<~5)
    }

    // ---- pool accumulation: lane owns cols lane*4..+3, rows in order ----
#pragma unroll
    for (int i = 0; i < 16; ++i) {
      int sg = __builtin_amdgcn_readfirstlane(stg[w][b].bat[i]);
      if (sg != curseg) {
        if (curseg >= 0) FLUSH(curseg);
        sum = (f32x4){0.f, 0.f, 0.f, 0.f};
        at  = (f32x4){0.f, 0.f, 0.f, 0.f};
        mx  = (f32x4){-INFINITY, -INFINITY, -INFINITY, -INFINITY};
        den = 0.f;
        curseg = sg;
      }
      float ei = __shfl(er[i & 3], (i >> 2) << 4, 64);
      const float4 v = *(const float4*)((const char*)&stg[w][b].xrow[i][0] +
                                        ((lane * 16) ^ ((i & 7) << 4)));
      den += ei;
      sum[0] += v.x; sum[1] += v.y; sum[2] += v.z; sum[3] += v.w;
      mx[0] = fmaxf(mx[0], v.x); mx[1] = fmaxf(mx[1], v.y);
      mx[2] = fmaxf(mx[2], v.z); mx[3] = fmaxf(mx[3], v.w);
      at[0] = fmaf(ei, v.x, at[0]); at[1] = fmaf(ei, v.y, at[1]);
      at[2] = fmaf(ei, v.z, at[2]); at[3] = fmaf(ei, v.w, at[3]);
    }

    if (t + 2 < tend) STAGE(t + 2, b);
  }
  if (curseg >= 0) FLUSH(curseg);
}

// ---------------------------------------------------------------------------
// Finalize + head: z = {sum/cnt, decode(max), attn/den}; y = z@wp+bp; LN.
// ---------------------------------------------------------------------------
__global__ __launch_bounds__(256) void head_ln(
    const float* __restrict__ gsum, const unsigned* __restrict__ gmx,
    const float* __restrict__ gat, const float* __restrict__ gden,
    const int* __restrict__ batch, const float* __restrict__ wp,
    const float* __restrict__ bp, const float* __restrict__ gam,
    const float* __restrict__ bet, float* __restrict__ out)
{
  const int g = blockIdx.x;
  const int tid = threadIdx.x;
  const int w = tid >> 6, lane = tid & 63;
  __shared__ int sb[2];
  __shared__ float z[768];
  __shared__ __align__(16) float part[4][256];
  __shared__ float red[256];

  if (tid < 2) sb[tid] = lower_bound_batch(batch, g + tid);
  __syncthreads();
  const float cnt = (float)(sb[1] - sb[0]);

  {
    const float s = gsum[(size_t)g * 256 + tid];
    const unsigned k = gmx[(size_t)g * 256 + tid];
    const unsigned u = (k & 0x80000000u) ? (k ^ 0x80000000u) : ~k;
    const float a = gat[(size_t)g * 256 + tid];
    const float den = gden[g];
    z[tid]       = (cnt > 0.f) ? s / cnt : 0.f;
    z[256 + tid] = (cnt > 0.f) ? __uint_as_float(u) : 0.f;
    z[512 + tid] = a / fmaxf(den, 1e-16f);
  }
  __syncthreads();

  f32x4 acc = (f32x4){0.f, 0.f, 0.f, 0.f};
  const float4* wp4 = (const float4*)wp;  // wp[k*256 + lane*4] = wp4[k*64 + lane]
  const int k0 = w * 192;
#pragma unroll 8
  for (int k = k0; k < k0 + 192; ++k) {
    float4 wv = wp4[(size_t)k * 64 + lane];
    float zk = z[k];
    acc[0] = fmaf(zk, wv.x, acc[0]);
    acc[1] = fmaf(zk, wv.y, acc[1]);
    acc[2] = fmaf(zk, wv.z, acc[2]);
    acc[3] = fmaf(zk, wv.w, acc[3]);
  }
  *(f32x4*)&part[w][lane * 4] = acc;
  __syncthreads();

  const int t = tid;
  float y = bp[t] + part[0][t] + part[1][t] + part[2][t] + part[3][t];

  red[t] = y;
  __syncthreads();
  for (int wd = 128; wd > 0; wd >>= 1) {
    if (t < wd) red[t] += red[t + wd];
    __syncthreads();
  }
  const float mu = red[0] * (1.f / 256.f);
  __syncthreads();
  float d = y - mu;
  red[t] = d * d;
  __syncthreads();
  for (int wd = 128; wd > 0; wd >>= 1) {
    if (t < wd) red[t] += red[t + wd];
    __syncthreads();
  }
  const float var = red[0] * (1.f / 256.f);
  const float is = rsqrtf(var + 1e-5f);
  out[(size_t)g * 256 + t] = fmaf(d * is, gam[t], bet[t]);
}

// ---------------------------------------------------------------------------
extern "C" void kernel_launch(void* const* d_in, const int* in_sizes, int n_in,
                              void* d_out, int out_size, void* d_ws, size_t ws_size,
                              hipStream_t stream) {
  const float* x   = (const float*)d_in[0];
  const int*   bat = (const int*)d_in[1];
  const float* w1  = (const float*)d_in[2];
  const float* b1  = (const float*)d_in[3];
  const float* w2  = (const float*)d_in[4];
  const float* b2  = (const float*)d_in[5];
  const float* wp  = (const float*)d_in[6];
  const float* bp  = (const float*)d_in[7];
  const float* gam = (const float*)d_in[8];
  const float* bet = (const float*)d_in[9];
  float* out = (float*)d_out;

  // ws: gsum[512*256] | gmx[512*256] | gat[512*256] | gden[512]
  float* gsum   = (float*)d_ws;
  unsigned* gmx = (unsigned*)(gsum + (size_t)NGRAPH * 256);
  float* gat    = (float*)(gmx + (size_t)NGRAPH * 256);
  float* gden   = gat + (size_t)NGRAPH * 256;
  const size_t zbytes = ((size_t)NGRAPH * 256 * 3 + NGRAPH) * 4;

  hipMemsetAsync(d_ws, 0, zbytes, stream);
  hipLaunchKernelGGL(fused_gate_pool, dim3(NBLK), dim3(256), 0, stream,
                     x, bat, w1, b1, w2, b2, gsum, gmx, gat, gden);
  hipLaunchKernelGGL(head_ln, dim3(NGRAPH), dim3(256), 0, stream,
                     gsum, gmx, gat, gden, bat, wp, bp, gam, bet, out);
}